// Round 7
// baseline (230.791 us; speedup 1.0000x reference)
//
#include <hip/hip_runtime.h>
#include <hip/hip_bf16.h>

// ProbAttention (Informer ProbSparse) on MI355X.
// Shapes: queries/keys/values (4, 4096, 8, 64) f32 in (b, l, h, d) layout.
// index_sample (4096, 45) int32. Output context (b, h, 4096, 64) f32.
//
// Pipeline (all fp32 — no fp32 MFMA on CDNA4; precision needed for top-k):
//   K1 compute_m   : m[b,h,l] = max_s(q.k_samp) - sum_s(q.k_samp)/4096
//                    block per (b,hg,l-grp): 1KB half-block gather, (b,hg)->XCD
//                    so the 4MB working set is L2-resident. 16-lane dot-reduce
//                    via DPP (VALU pipe), not shfl (DS pipe).
//   K2a topk_p1    : per (b,h,512-slice) top-45 candidates (packed u64 keys)
//   K2b topk_p2    : merge 8x45 candidates -> global top-45 (tie: lowest idx)
//   K3a meanv_part : partial sums of v over l (2048 blocks, full chip)
//   K3b meanv_final: reduce 64 partials -> meanv
//   K3c fill       : out[...] = meanv broadcast (32 MB write)
//   K4 scores      : split-K flash, row-split: block = (b,h,chunk,rowgroup of
//                    <=12 rows): partial softmax(Qr K^T * 0.125), P@V -> ws.
//                    16KB LDS/block, 2048 blocks -> occupancy ~50-60%.
//   K5 combine     : merge 16 chunk partials, scatter to out rows m_top[u]

#define NB 4
#define NH 8
#define NL 4096
#define ND 64
#define NS 45          // U = n_top = 45
#define NSR 12         // rows per k_scores rowgroup (4 groups: 12,12,12,9)
#define SCALE 0.125f   // 1/sqrt(64)
#define NCHUNK 16
#define CHUNK 256

typedef float floatx4 __attribute__((ext_vector_type(4)));

static __device__ __forceinline__ float neg_inf() { return -__builtin_inff(); }

// VALU-pipe cross-lane add via DPP (no DS traffic).
template <int CTRL>
static __device__ __forceinline__ float dpp_add(float x) {
  int y = __builtin_amdgcn_update_dpp(0, __builtin_bit_cast(int, x), CTRL,
                                      0xF, 0xF, true);
  return x + __builtin_bit_cast(float, y);
}
// Sum over 16 contiguous lanes; every lane ends with the group total.
static __device__ __forceinline__ float red16(float x) {
  x = dpp_add<0x140>(x);  // row_mirror      (fold 16 -> 8)
  x = dpp_add<0x141>(x);  // row_half_mirror (fold 8 -> 4)
  x = dpp_add<0x4E>(x);   // quad_perm [2,3,0,1] = xor2
  x = dpp_add<0xB1>(x);   // quad_perm [1,0,3,2] = xor1
  return x;
}

// ---------------- K1: sampled-dot m ----------------
// Block per (b, hg, l-group of 4). Wave w = one l. 16-lane group g = head hg*4+g.
// Per sample: 1KB contiguous K half-block (64 lanes x float4), fully coalesced,
// L2-resident (4MB working set per (b,hg) pinned to one XCD via blockIdx&7).
__global__ __launch_bounds__(256) void k_compute_m(
    const float* __restrict__ q, const float* __restrict__ k,
    const int* __restrict__ idxs, float* __restrict__ m_out)
{
  __shared__ int sidx[4][NS];
  int gb = blockIdx.x;                 // 8192 blocks
  int pair = gb & 7;                   // (b,hg) -> XCD (round-robin dispatch)
  int b = pair >> 1, hg = pair & 1;
  int lg = gb >> 3;                    // 0..1023
  int t = threadIdx.x, w = t >> 6, lane = t & 63, g = lane >> 4;
  int l = lg * 4 + w;

  if (lane < NS) sidx[w][lane] = idxs[l * NS + lane];  // wave-private row

  // Q: heads hg*4..hg*4+3 of row l, 1KB contiguous. Non-temporal (stream once,
  // don't evict the L2-resident K set).
  const floatx4* q4 =
      (const floatx4*)(q + ((size_t)(b * NL + l) * NH + hg * 4) * ND);
  floatx4 qr = __builtin_nontemporal_load(q4 + lane);

  // K half-block base for this (b,hg): row ki at +ki*128 float4s, 1KB each.
  const floatx4* kb4 = (const floatx4*)k + ((size_t)b * NL * NH + hg * 4) * 16;

  float mx = neg_inf(), sm = 0.f;
#pragma unroll 5
  for (int s = 0; s < NS; ++s) {
    int ki = sidx[w][s];
    floatx4 kk = kb4[(size_t)ki * 128 + lane];
    float p = kk.x * qr.x + kk.y * qr.y + kk.z * qr.z + kk.w * qr.w;
    p = red16(p);                      // 16-lane dot, VALU-only
    mx = fmaxf(mx, p);
    sm += p;
  }
  if ((lane & 15) == 0)
    m_out[((size_t)b * NH + hg * 4 + g) * NL + l] = mx - sm * (1.0f / 4096.0f);
}

// ---------------- K2a: per-slice top-45 candidates ----------------
// Block = (bh, 512-slice). Keys: monotone(float) || ~index (exact tie-break).
__global__ __launch_bounds__(256) void k_topk_p1(
    const float* __restrict__ m_in, unsigned long long* __restrict__ cand)
{
  __shared__ unsigned long long keys[512];
  __shared__ unsigned long long wred[4];
  int blk = blockIdx.x;                // bh*8 + slice
  int bh = blk >> 3, slice = blk & 7;
  int t = threadIdx.x, wid = t >> 6, lane = t & 63;
  int base = slice * 512;
  for (int i = t; i < 512; i += 256) {
    float v = m_in[bh * NL + base + i];
    unsigned u = __float_as_uint(v);
    u ^= (u >> 31) ? 0xFFFFFFFFu : 0x80000000u;  // monotone mapping
    keys[i] = ((unsigned long long)u << 32) | (unsigned)(~(unsigned)(base + i));
  }
  __syncthreads();
  for (int it = 0; it < NS; ++it) {
    unsigned long long k0 = keys[t], k1 = keys[t + 256];
    unsigned long long best = k0 > k1 ? k0 : k1;
#pragma unroll
    for (int off = 32; off; off >>= 1) {
      unsigned long long o = __shfl_xor(best, off);
      if (o > best) best = o;
    }
    if (lane == 0) wred[wid] = best;
    __syncthreads();
    if (t == 0) {
      unsigned long long b0 = wred[0];
      if (wred[1] > b0) b0 = wred[1];
      if (wred[2] > b0) b0 = wred[2];
      if (wred[3] > b0) b0 = wred[3];
      cand[blk * NS + it] = b0;
      int gi = (int)(~(unsigned)(b0 & 0xFFFFFFFFull));
      keys[gi - base] = 0;
    }
    __syncthreads();
  }
}

// ---------------- K2b: merge 8x45 candidates -> top-45 ----------------
__global__ __launch_bounds__(256) void k_topk_p2(
    const unsigned long long* __restrict__ cand, int* __restrict__ mtop)
{
  __shared__ unsigned long long keys[8 * NS];  // 360
  __shared__ unsigned long long wred[4];
  __shared__ unsigned long long sbest;
  int bh = blockIdx.x;
  int t = threadIdx.x, wid = t >> 6, lane = t & 63;
  for (int i = t; i < 8 * NS; i += 256) keys[i] = cand[bh * 8 * NS + i];
  __syncthreads();
  for (int it = 0; it < NS; ++it) {
    unsigned long long best = (t < 8 * NS) ? keys[t] : 0ull;
    if (t + 256 < 8 * NS) {
      unsigned long long k1 = keys[t + 256];
      if (k1 > best) best = k1;
    }
#pragma unroll
    for (int off = 32; off; off >>= 1) {
      unsigned long long o = __shfl_xor(best, off);
      if (o > best) best = o;
    }
    if (lane == 0) wred[wid] = best;
    __syncthreads();
    if (t == 0) {
      unsigned long long b0 = wred[0];
      if (wred[1] > b0) b0 = wred[1];
      if (wred[2] > b0) b0 = wred[2];
      if (wred[3] > b0) b0 = wred[3];
      sbest = b0;
      mtop[bh * NS + it] = (int)(~(unsigned)(b0 & 0xFFFFFFFFull));
    }
    __syncthreads();
    unsigned long long bb = sbest;     // keys are unique -> exact match zeroing
    if (t < 8 * NS && keys[t] == bb) keys[t] = 0;
    if (t + 256 < 8 * NS && keys[t + 256] == bb) keys[t + 256] = 0;
    __syncthreads();
  }
}

// ---------------- K3a: partial mean of v over l ----------------
// grid (32 bh, 64 chunks); block sums 64 consecutive l rows.
__global__ __launch_bounds__(256) void k_meanv_part(
    const float* __restrict__ v, float* __restrict__ vpart)
{
  __shared__ float part[4][ND];
  int bh = blockIdx.x, c = blockIdx.y;
  int b = bh >> 3, h = bh & 7;
  int t = threadIdx.x, d = t & 63, g = t >> 6;
  float a0 = 0.f, a1 = 0.f, a2 = 0.f, a3 = 0.f;
  const float* vb = v + ((size_t)(b * NL + c * 64) * NH + h) * ND + d;
#pragma unroll
  for (int i = 0; i < 4; i++) {
    a0 += vb[(size_t)(g + 4 * (4 * i + 0)) * NH * ND];
    a1 += vb[(size_t)(g + 4 * (4 * i + 1)) * NH * ND];
    a2 += vb[(size_t)(g + 4 * (4 * i + 2)) * NH * ND];
    a3 += vb[(size_t)(g + 4 * (4 * i + 3)) * NH * ND];
  }
  part[g][d] = (a0 + a1) + (a2 + a3);
  __syncthreads();
  if (g == 0) {
    float s = part[0][d] + part[1][d] + part[2][d] + part[3][d];
    vpart[(bh * 64 + c) * ND + d] = s;
  }
}

// ---------------- K3b: reduce partials -> meanv ----------------
__global__ __launch_bounds__(64) void k_meanv_final(
    const float* __restrict__ vpart, float* __restrict__ meanv)
{
  int bh = blockIdx.x, d = threadIdx.x;
  float s = 0.f;
  for (int c = 0; c < 64; c++) s += vpart[(bh * 64 + c) * ND + d];
  meanv[bh * ND + d] = s * (1.0f / 4096.0f);
}

// ---------------- K3c: fill output with meanv ----------------
__global__ __launch_bounds__(256) void k_fill(
    const float* __restrict__ meanv, float4* __restrict__ out4)
{
  const int total = NB * NH * NL * ND / 4;  // 2M float4
  const float4* mv4 = (const float4*)meanv;
  for (int i = blockIdx.x * 256 + threadIdx.x; i < total; i += gridDim.x * 256) {
    int bh = i >> 16;       // 65536 float4 per (b,h)
    int d4 = i & 15;
    out4[i] = mv4[bh * 16 + d4];
  }
}

// ---------------- K4: split-K scores+softmax+PV partials (row-split) ----------------
// Block = (b,h, chunk of 256 keys, rowgroup of <=12 rows), 256 threads.
// Grid order: rowgroup fastest -> 4 blocks sharing one K/V chunk are adjacent.
__global__ __launch_bounds__(256) void k_scores(
    const float* __restrict__ q, const float* __restrict__ k,
    const float* __restrict__ v, const int* __restrict__ mtop,
    float* __restrict__ mc_out, float* __restrict__ lc_out,
    float* __restrict__ op_out)
{
  __shared__ float QLDS[NSR * ND];     // 12x64 = 3KB
  __shared__ float SLDS[NSR * 260];    // 12 rows, 260-stride (pad) = 12.5KB
  __shared__ int mt[NSR];
  __shared__ float mcs[NSR], lcs[NSR];

  int gb = blockIdx.x;                 // 2048 blocks
  int xcd = gb & 7, seq = gb >> 3;     // 256 per XCD
  int bh = xcd * 4 + (seq >> 6);
  int c = (seq >> 2) & 15;
  int rg = seq & 3;                    // rowgroup: rows rg*12 .. rg*12+nr-1
  int nr = (rg == 3) ? (NS - 3 * NSR) : NSR;   // 12,12,12,9
  int b = bh >> 3, h = bh & 7;
  int t = threadIdx.x;
  int wid = t >> 6, lane = t & 63;

  if (t < nr) mt[t] = mtop[bh * NS + rg * NSR + t];
  __syncthreads();

  // stage Qr (nr rows) into LDS: nr*16 float4 (<=192, one pass)
  const float4* q4 = (const float4*)q;
  float4* QL4 = (float4*)QLDS;
  if (t < nr * 16) {
    int u = t >> 4, j = t & 15;
    QL4[t] = q4[((size_t)(b * NL + mt[u]) * NH + h) * 16 + j];
  }
  __syncthreads();

  // Phase B: thread t owns key column kk=t; K row held in 16 float4 regs.
  {
    int kk = t;
    const float4* k4 =
        (const float4*)(k + ((size_t)(b * NL + c * CHUNK + kk) * NH + h) * ND);
    float4 kr[16];
#pragma unroll
    for (int j = 0; j < 16; j++) kr[j] = k4[j];
    for (int u = 0; u < nr; ++u) {
      float dot = 0.f;
#pragma unroll
      for (int j = 0; j < 16; j++) {
        float4 qq = QL4[u * 16 + j];  // broadcast read
        dot += qq.x * kr[j].x + qq.y * kr[j].y + qq.z * kr[j].z + qq.w * kr[j].w;
      }
      SLDS[u * 260 + kk] = dot * SCALE;
    }
  }
  __syncthreads();

  // Phase B2: per-row chunk softmax (max, exp, sum), exp written back.
  for (int u = wid; u < nr; u += 4) {
    float4 sv = *(const float4*)&SLDS[u * 260 + lane * 4];
    float mx = fmaxf(fmaxf(sv.x, sv.y), fmaxf(sv.z, sv.w));
#pragma unroll
    for (int off = 32; off; off >>= 1) mx = fmaxf(mx, __shfl_xor(mx, off));
    float e0 = expf(sv.x - mx), e1 = expf(sv.y - mx);
    float e2 = expf(sv.z - mx), e3 = expf(sv.w - mx);
    float s = e0 + e1 + e2 + e3;
#pragma unroll
    for (int off = 32; off; off >>= 1) s += __shfl_xor(s, off);
    *(float4*)&SLDS[u * 260 + lane * 4] = make_float4(e0, e1, e2, e3);
    if (lane == 0) { mcs[u] = mx; lcs[u] = s; }
  }
  __syncthreads();

  // Phase C: O_partial = P @ V_chunk. Wave w owns rows u = w+4i; lane = d.
  float acc[3];
#pragma unroll
  for (int i = 0; i < 3; i++) acc[i] = 0.f;
  const float* vbase = v + ((size_t)(b * NL + c * CHUNK) * NH + h) * ND + lane;
  for (int kb = 0; kb < 64; ++kb) {
    float vd0 = vbase[(size_t)(kb * 4 + 0) * NH * ND];
    float vd1 = vbase[(size_t)(kb * 4 + 1) * NH * ND];
    float vd2 = vbase[(size_t)(kb * 4 + 2) * NH * ND];
    float vd3 = vbase[(size_t)(kb * 4 + 3) * NH * ND];
#pragma unroll
    for (int i = 0; i < 3; i++) {
      int u = wid + 4 * i;
      if (u < nr) {
        float4 p4 = *(const float4*)&SLDS[u * 260 + kb * 4];  // broadcast
        acc[i] += p4.x * vd0 + p4.y * vd1 + p4.z * vd2 + p4.w * vd3;
      }
    }
  }
#pragma unroll
  for (int i = 0; i < 3; i++) {
    int u = wid + 4 * i;
    if (u < nr)
      op_out[(((size_t)bh * NCHUNK + c) * NS + rg * NSR + u) * ND + lane] = acc[i];
  }
  if (t < nr) {
    mc_out[(bh * NCHUNK + c) * NS + rg * NSR + t] = mcs[t];
    lc_out[(bh * NCHUNK + c) * NS + rg * NSR + t] = lcs[t];
  }
}

// ---------------- K5: combine partials + scatter ----------------
__global__ __launch_bounds__(256) void k_combine(
    const float* __restrict__ mc, const float* __restrict__ lc,
    const float* __restrict__ op, const int* __restrict__ mtop,
    float* __restrict__ out)
{
  int gw = blockIdx.x * 4 + (threadIdx.x >> 6);  // 1440 waves
  int lane = threadIdx.x & 63;
  int bh = gw / NS, u = gw % NS;
  float M = neg_inf();
  for (int c = 0; c < NCHUNK; c++)
    M = fmaxf(M, mc[(bh * NCHUNK + c) * NS + u]);
  float Lsum = 0.f, O = 0.f;
  for (int c = 0; c < NCHUNK; c++) {
    float e = expf(mc[(bh * NCHUNK + c) * NS + u] - M);
    Lsum += lc[(bh * NCHUNK + c) * NS + u] * e;
    O += op[(((size_t)bh * NCHUNK + c) * NS + u) * ND + lane] * e;
  }
  int row = mtop[bh * NS + u];
  out[((size_t)bh * NL + row) * ND + lane] = O / Lsum;
}

extern "C" void kernel_launch(void* const* d_in, const int* in_sizes, int n_in,
                              void* d_out, int out_size, void* d_ws, size_t ws_size,
                              hipStream_t stream) {
  const float* q = (const float*)d_in[0];
  const float* k = (const float*)d_in[1];
  const float* v = (const float*)d_in[2];
  const int* idxs = (const int*)d_in[3];
  float* out = (float*)d_out;
  float* ws = (float*)d_ws;

  // workspace layout (floats): total ~1.66M floats = 6.62 MB
  float* m_ws  = ws;                    // 131072
  int*   mtop  = (int*)(ws + 131072);   // 1440 ints
  float* meanv = ws + 132512;           // 2048
  float* mc    = ws + 134560;           // 32*16*45 = 23040
  float* lc    = ws + 157600;           // 23040
  float* op    = ws + 180640;           // 32*16*45*64 = 1474560
  // Aliases inside op (consumed before k_scores writes op; serial stream):
  //   vpart: op[0 .. 131072)           (meanv partials)
  //   cand : op[131072 .. 154112)      (topk candidates, 11520 u64)
  float* vpart = op;
  unsigned long long* cand = (unsigned long long*)(op + 131072);

  hipLaunchKernelGGL(k_compute_m,   dim3(8192),      dim3(256), 0, stream, q, k, idxs, m_ws);
  hipLaunchKernelGGL(k_topk_p1,     dim3(256),       dim3(256), 0, stream, m_ws, cand);
  hipLaunchKernelGGL(k_topk_p2,     dim3(32),        dim3(256), 0, stream, cand, mtop);
  hipLaunchKernelGGL(k_meanv_part,  dim3(32, 64),    dim3(256), 0, stream, v, vpart);
  hipLaunchKernelGGL(k_meanv_final, dim3(32),        dim3(64),  0, stream, vpart, meanv);
  hipLaunchKernelGGL(k_fill,        dim3(2048),      dim3(256), 0, stream, meanv, (float4*)out);
  hipLaunchKernelGGL(k_scores,      dim3(2048),      dim3(256), 0, stream, q, k, v, mtop, mc, lc, op);
  hipLaunchKernelGGL(k_combine,     dim3(360),       dim3(256), 0, stream, mc, lc, op, mtop, out);
}

// Round 8
// 186.614 us; speedup vs baseline: 1.2367x; 1.2367x over previous
//
#include <hip/hip_runtime.h>
#include <hip/hip_bf16.h>

// ProbAttention (Informer ProbSparse) on MI355X.
// Shapes: queries/keys/values (4, 4096, 8, 64) f32 in (b, l, h, d) layout.
// index_sample (4096, 45) int32. Output context (b, h, 4096, 64) f32.
//
// Pipeline (all fp32 — no fp32 MFMA on CDNA4; precision needed for top-k):
//   K1 compute_m   : m[b,h,l] = max_s(q.k_samp) - sum_s(q.k_samp)/4096
//                    1KB half-block gather, (b,hg)->XCD (L2-resident), DPP
//                    16-lane reduce, readfirstlane-hoisted gather address.
//   K2a topk_p1    : per (b,h,512-slice) top-45 candidates (packed u64 keys)
//   K2b topk_p2    : merge 8x45 candidates -> global top-45 (tie: lowest idx)
//   K3a meanv_part : partial sums of v over l (2048 blocks, full chip)
//   K3b meanv_final: reduce 64 partials -> meanv
//   K3c fill       : out[...] = meanv broadcast (32 MB write)
//   K4 scores      : block=(b,h,chunk of 256), 1024 threads (16 waves ->
//                    32 waves/CU at 2 blocks/CU). QK^T quad-per-key with
//                    coalesced K loads + DPP quad reduce; chunk softmax;
//                    P@V with coalesced V. Partials -> ws.
//   K5 combine     : merge 16 chunk partials, scatter to out rows m_top[u]

#define NB 4
#define NH 8
#define NL 4096
#define ND 64
#define NS 45          // U = n_top = 45
#define SCALE 0.125f   // 1/sqrt(64)
#define NCHUNK 16
#define CHUNK 256

typedef float floatx4 __attribute__((ext_vector_type(4)));

static __device__ __forceinline__ float neg_inf() { return -__builtin_inff(); }

// VALU-pipe cross-lane add via DPP (no DS traffic).
template <int CTRL>
static __device__ __forceinline__ float dpp_add(float x) {
  int y = __builtin_amdgcn_update_dpp(0, __builtin_bit_cast(int, x), CTRL,
                                      0xF, 0xF, true);
  return x + __builtin_bit_cast(float, y);
}
// Sum over 16 contiguous lanes; every lane ends with the group total.
static __device__ __forceinline__ float red16(float x) {
  x = dpp_add<0x140>(x);  // row_mirror      (fold 16 -> 8)
  x = dpp_add<0x141>(x);  // row_half_mirror (fold 8 -> 4)
  x = dpp_add<0x4E>(x);   // quad_perm [2,3,0,1] = xor2
  x = dpp_add<0xB1>(x);   // quad_perm [1,0,3,2] = xor1
  return x;
}
// Sum over each 4-lane quad (butterfly), all 4 lanes get the quad total.
static __device__ __forceinline__ float red4(float x) {
  x = dpp_add<0xB1>(x);   // xor1
  x = dpp_add<0x4E>(x);   // xor2
  return x;
}

// ---------------- K1: sampled-dot m ----------------
// Block per (b, hg, l-group of 4). Wave w = one l. 16-lane group g = head hg*4+g.
// Per sample: 1KB contiguous K half-block (64 lanes x float4), fully coalesced,
// L2-resident (4MB working set per (b,hg) pinned to one XCD via blockIdx&7).
__global__ __launch_bounds__(256) void k_compute_m(
    const float* __restrict__ q, const float* __restrict__ k,
    const int* __restrict__ idxs, float* __restrict__ m_out)
{
  __shared__ int sidx[4][NS];
  int gb = blockIdx.x;                 // 8192 blocks
  int pair = gb & 7;                   // (b,hg) -> XCD (round-robin dispatch)
  int b = pair >> 1, hg = pair & 1;
  int lg = gb >> 3;                    // 0..1023
  int t = threadIdx.x, w = t >> 6, lane = t & 63, g = lane >> 4;
  int l = lg * 4 + w;

  if (lane < NS) sidx[w][lane] = idxs[l * NS + lane];  // wave-private row

  // Q: heads hg*4..hg*4+3 of row l, 1KB contiguous. Non-temporal (stream once,
  // don't evict the L2-resident K set).
  const floatx4* q4 =
      (const floatx4*)(q + ((size_t)(b * NL + l) * NH + hg * 4) * ND);
  floatx4 qr = __builtin_nontemporal_load(q4 + lane);

  // K half-block base for this (b,hg): row ki at +ki*128 float4s, 1KB each.
  const floatx4* kb4 = (const floatx4*)k + ((size_t)b * NL * NH + hg * 4) * 16;

  float mx = neg_inf(), sm = 0.f;
#pragma unroll 5
  for (int s = 0; s < NS; ++s) {
    int ki = __builtin_amdgcn_readfirstlane(sidx[w][s]);  // uniform -> SALU addr
    floatx4 kk = kb4[(size_t)ki * 128 + lane];
    float p = kk.x * qr.x + kk.y * qr.y + kk.z * qr.z + kk.w * qr.w;
    p = red16(p);                      // 16-lane dot, VALU-only
    mx = fmaxf(mx, p);
    sm += p;
  }
  if ((lane & 15) == 0)
    m_out[((size_t)b * NH + hg * 4 + g) * NL + l] = mx - sm * (1.0f / 4096.0f);
}

// ---------------- K2a: per-slice top-45 candidates ----------------
// Block = (bh, 512-slice). Keys: monotone(float) || ~index (exact tie-break).
__global__ __launch_bounds__(256) void k_topk_p1(
    const float* __restrict__ m_in, unsigned long long* __restrict__ cand)
{
  __shared__ unsigned long long keys[512];
  __shared__ unsigned long long wred[4];
  int blk = blockIdx.x;                // bh*8 + slice
  int bh = blk >> 3, slice = blk & 7;
  int t = threadIdx.x, wid = t >> 6, lane = t & 63;
  int base = slice * 512;
  for (int i = t; i < 512; i += 256) {
    float v = m_in[bh * NL + base + i];
    unsigned u = __float_as_uint(v);
    u ^= (u >> 31) ? 0xFFFFFFFFu : 0x80000000u;  // monotone mapping
    keys[i] = ((unsigned long long)u << 32) | (unsigned)(~(unsigned)(base + i));
  }
  __syncthreads();
  for (int it = 0; it < NS; ++it) {
    unsigned long long k0 = keys[t], k1 = keys[t + 256];
    unsigned long long best = k0 > k1 ? k0 : k1;
#pragma unroll
    for (int off = 32; off; off >>= 1) {
      unsigned long long o = __shfl_xor(best, off);
      if (o > best) best = o;
    }
    if (lane == 0) wred[wid] = best;
    __syncthreads();
    if (t == 0) {
      unsigned long long b0 = wred[0];
      if (wred[1] > b0) b0 = wred[1];
      if (wred[2] > b0) b0 = wred[2];
      if (wred[3] > b0) b0 = wred[3];
      cand[blk * NS + it] = b0;
      int gi = (int)(~(unsigned)(b0 & 0xFFFFFFFFull));
      keys[gi - base] = 0;
    }
    __syncthreads();
  }
}

// ---------------- K2b: merge 8x45 candidates -> top-45 ----------------
__global__ __launch_bounds__(256) void k_topk_p2(
    const unsigned long long* __restrict__ cand, int* __restrict__ mtop)
{
  __shared__ unsigned long long keys[8 * NS];  // 360
  __shared__ unsigned long long wred[4];
  __shared__ unsigned long long sbest;
  int bh = blockIdx.x;
  int t = threadIdx.x, wid = t >> 6, lane = t & 63;
  for (int i = t; i < 8 * NS; i += 256) keys[i] = cand[bh * 8 * NS + i];
  __syncthreads();
  for (int it = 0; it < NS; ++it) {
    unsigned long long best = (t < 8 * NS) ? keys[t] : 0ull;
    if (t + 256 < 8 * NS) {
      unsigned long long k1 = keys[t + 256];
      if (k1 > best) best = k1;
    }
#pragma unroll
    for (int off = 32; off; off >>= 1) {
      unsigned long long o = __shfl_xor(best, off);
      if (o > best) best = o;
    }
    if (lane == 0) wred[wid] = best;
    __syncthreads();
    if (t == 0) {
      unsigned long long b0 = wred[0];
      if (wred[1] > b0) b0 = wred[1];
      if (wred[2] > b0) b0 = wred[2];
      if (wred[3] > b0) b0 = wred[3];
      sbest = b0;
      mtop[bh * NS + it] = (int)(~(unsigned)(b0 & 0xFFFFFFFFull));
    }
    __syncthreads();
    unsigned long long bb = sbest;     // keys are unique -> exact match zeroing
    if (t < 8 * NS && keys[t] == bb) keys[t] = 0;
    if (t + 256 < 8 * NS && keys[t + 256] == bb) keys[t + 256] = 0;
    __syncthreads();
  }
}

// ---------------- K3a: partial mean of v over l ----------------
// grid (32 bh, 64 chunks); block sums 64 consecutive l rows.
__global__ __launch_bounds__(256) void k_meanv_part(
    const float* __restrict__ v, float* __restrict__ vpart)
{
  __shared__ float part[4][ND];
  int bh = blockIdx.x, c = blockIdx.y;
  int b = bh >> 3, h = bh & 7;
  int t = threadIdx.x, d = t & 63, g = t >> 6;
  float a0 = 0.f, a1 = 0.f, a2 = 0.f, a3 = 0.f;
  const float* vb = v + ((size_t)(b * NL + c * 64) * NH + h) * ND + d;
#pragma unroll
  for (int i = 0; i < 4; i++) {
    a0 += vb[(size_t)(g + 4 * (4 * i + 0)) * NH * ND];
    a1 += vb[(size_t)(g + 4 * (4 * i + 1)) * NH * ND];
    a2 += vb[(size_t)(g + 4 * (4 * i + 2)) * NH * ND];
    a3 += vb[(size_t)(g + 4 * (4 * i + 3)) * NH * ND];
  }
  part[g][d] = (a0 + a1) + (a2 + a3);
  __syncthreads();
  if (g == 0) {
    float s = part[0][d] + part[1][d] + part[2][d] + part[3][d];
    vpart[(bh * 64 + c) * ND + d] = s;
  }
}

// ---------------- K3b: reduce partials -> meanv ----------------
__global__ __launch_bounds__(64) void k_meanv_final(
    const float* __restrict__ vpart, float* __restrict__ meanv)
{
  int bh = blockIdx.x, d = threadIdx.x;
  float s = 0.f;
  for (int c = 0; c < 64; c++) s += vpart[(bh * 64 + c) * ND + d];
  meanv[bh * ND + d] = s * (1.0f / 4096.0f);
}

// ---------------- K3c: fill output with meanv ----------------
__global__ __launch_bounds__(256) void k_fill(
    const float* __restrict__ meanv, float4* __restrict__ out4)
{
  const int total = NB * NH * NL * ND / 4;  // 2M float4
  const float4* mv4 = (const float4*)meanv;
  for (int i = blockIdx.x * 256 + threadIdx.x; i < total; i += gridDim.x * 256) {
    int bh = i >> 16;       // 65536 float4 per (b,h)
    int d4 = i & 15;
    out4[i] = mv4[bh * 16 + d4];
  }
}

// ---------------- K4: scores+softmax+PV partials (16 waves/block) ----------------
// Block = (b,h, chunk of 256 keys), 1024 threads = 16 waves.
// Phase B: quad-per-key QK^T, coalesced K, DPP quad reduce (one pass, 16 keys/wave).
// Phase B2: full-chunk softmax per row.  Phase C: P@V, coalesced V, 3 rows/wave.
__global__ __launch_bounds__(1024) void k_scores(
    const float* __restrict__ q, const float* __restrict__ k,
    const float* __restrict__ v, const int* __restrict__ mtop,
    float* __restrict__ mc_out, float* __restrict__ lc_out,
    float* __restrict__ op_out)
{
  __shared__ float QLDS[NS * ND];     // 45x64 = 11.5KB
  __shared__ float SLDS[NS * 260];    // 45 rows, 260-stride (pad) = 46.8KB
  __shared__ int mt[NS];
  __shared__ float mcs[NS], lcs[NS];

  int gb = blockIdx.x;
  int xcd = gb & 7, seq = gb >> 3;    // 512 blocks: 4 bh per XCD
  int bh = xcd * 4 + (seq >> 4);
  int c = seq & 15;
  int b = bh >> 3, h = bh & 7;
  int t = threadIdx.x;                // 0..1023
  int wid = t >> 6, lane = t & 63;

  if (t < NS) mt[t] = mtop[bh * NS + t];
  __syncthreads();

  // stage Qr (45 rows) into LDS: 720 float4, one per thread t<720
  const float4* q4 = (const float4*)q;
  float4* QL4 = (float4*)QLDS;
  if (t < NS * 16) {
    int u = t >> 4, j = t & 15;
    QL4[t] = q4[((size_t)(b * NL + mt[u]) * NH + h) * 16 + j];
  }
  __syncthreads();

  // Phase B: quad owns key kk; lane holds contiguous 64B segment of K row.
  {
    int kk = wid * 16 + (lane >> 2);   // 0..255 (16 waves x 16 keys)
    int seg = lane & 3;
    const float4* k4 =
        (const float4*)(k + ((size_t)(b * NL + c * CHUNK + kk) * NH + h) * ND)
        + seg * 4;
    float4 k0 = k4[0], k1 = k4[1], k2 = k4[2], k3 = k4[3];
    const float4* qp = QL4 + seg * 4;
    for (int u = 0; u < NS; ++u) {
      float4 a0 = qp[u * 16 + 0], a1 = qp[u * 16 + 1];
      float4 a2 = qp[u * 16 + 2], a3 = qp[u * 16 + 3];
      float dot = a0.x * k0.x + a0.y * k0.y + a0.z * k0.z + a0.w * k0.w
                + a1.x * k1.x + a1.y * k1.y + a1.z * k1.z + a1.w * k1.w
                + a2.x * k2.x + a2.y * k2.y + a2.z * k2.z + a2.w * k2.w
                + a3.x * k3.x + a3.y * k3.y + a3.z * k3.z + a3.w * k3.w;
      dot = red4(dot);                 // quad total, VALU-only
      if (seg == 0) SLDS[u * 260 + kk] = dot * SCALE;
    }
  }
  __syncthreads();

  // Phase B2: per-row chunk softmax (max, exp, sum), exp written back.
  for (int u = wid; u < NS; u += 16) {
    float4 sv = *(const float4*)&SLDS[u * 260 + lane * 4];
    float mx = fmaxf(fmaxf(sv.x, sv.y), fmaxf(sv.z, sv.w));
#pragma unroll
    for (int off = 32; off; off >>= 1) mx = fmaxf(mx, __shfl_xor(mx, off));
    float e0 = expf(sv.x - mx), e1 = expf(sv.y - mx);
    float e2 = expf(sv.z - mx), e3 = expf(sv.w - mx);
    float s = e0 + e1 + e2 + e3;
#pragma unroll
    for (int off = 32; off; off >>= 1) s += __shfl_xor(s, off);
    *(float4*)&SLDS[u * 260 + lane * 4] = make_float4(e0, e1, e2, e3);
    if (lane == 0) { mcs[u] = mx; lcs[u] = s; }
  }
  __syncthreads();

  // Phase C: O_partial = P @ V_chunk. Wave w owns rows u = w+16i; lane = d.
  float acc[3];
#pragma unroll
  for (int i = 0; i < 3; i++) acc[i] = 0.f;
  const float* vbase = v + ((size_t)(b * NL + c * CHUNK) * NH + h) * ND + lane;
  for (int kb = 0; kb < 64; ++kb) {
    float vd0 = vbase[(size_t)(kb * 4 + 0) * NH * ND];
    float vd1 = vbase[(size_t)(kb * 4 + 1) * NH * ND];
    float vd2 = vbase[(size_t)(kb * 4 + 2) * NH * ND];
    float vd3 = vbase[(size_t)(kb * 4 + 3) * NH * ND];
#pragma unroll
    for (int i = 0; i < 3; i++) {
      int u = wid + 16 * i;
      if (u < NS) {
        float4 p4 = *(const float4*)&SLDS[u * 260 + kb * 4];  // broadcast
        acc[i] += p4.x * vd0 + p4.y * vd1 + p4.z * vd2 + p4.w * vd3;
      }
    }
  }
#pragma unroll
  for (int i = 0; i < 3; i++) {
    int u = wid + 16 * i;
    if (u < NS)
      op_out[(((size_t)bh * NCHUNK + c) * NS + u) * ND + lane] = acc[i];
  }
  if (t < NS) {
    mc_out[(bh * NCHUNK + c) * NS + t] = mcs[t];
    lc_out[(bh * NCHUNK + c) * NS + t] = lcs[t];
  }
}

// ---------------- K5: combine partials + scatter ----------------
__global__ __launch_bounds__(256) void k_combine(
    const float* __restrict__ mc, const float* __restrict__ lc,
    const float* __restrict__ op, const int* __restrict__ mtop,
    float* __restrict__ out)
{
  int gw = blockIdx.x * 4 + (threadIdx.x >> 6);  // 1440 waves
  int lane = threadIdx.x & 63;
  int bh = gw / NS, u = gw % NS;
  float M = neg_inf();
  for (int c = 0; c < NCHUNK; c++)
    M = fmaxf(M, mc[(bh * NCHUNK + c) * NS + u]);
  float Lsum = 0.f, O = 0.f;
  for (int c = 0; c < NCHUNK; c++) {
    float e = expf(mc[(bh * NCHUNK + c) * NS + u] - M);
    Lsum += lc[(bh * NCHUNK + c) * NS + u] * e;
    O += op[(((size_t)bh * NCHUNK + c) * NS + u) * ND + lane] * e;
  }
  int row = mtop[bh * NS + u];
  out[((size_t)bh * NL + row) * ND + lane] = O / Lsum;
}

extern "C" void kernel_launch(void* const* d_in, const int* in_sizes, int n_in,
                              void* d_out, int out_size, void* d_ws, size_t ws_size,
                              hipStream_t stream) {
  const float* q = (const float*)d_in[0];
  const float* k = (const float*)d_in[1];
  const float* v = (const float*)d_in[2];
  const int* idxs = (const int*)d_in[3];
  float* out = (float*)d_out;
  float* ws = (float*)d_ws;

  // workspace layout (floats): total ~1.66M floats = 6.62 MB
  float* m_ws  = ws;                    // 131072
  int*   mtop  = (int*)(ws + 131072);   // 1440 ints
  float* meanv = ws + 132512;           // 2048
  float* mc    = ws + 134560;           // 32*16*45 = 23040
  float* lc    = ws + 157600;           // 23040
  float* op    = ws + 180640;           // 32*16*45*64 = 1474560
  // Aliases inside op (consumed before k_scores writes op; serial stream):
  //   vpart: op[0 .. 131072)           (meanv partials)
  //   cand : op[131072 .. 154112)      (topk candidates, 11520 u64)
  float* vpart = op;
  unsigned long long* cand = (unsigned long long*)(op + 131072);

  hipLaunchKernelGGL(k_compute_m,   dim3(8192),      dim3(256),  0, stream, q, k, idxs, m_ws);
  hipLaunchKernelGGL(k_topk_p1,     dim3(256),       dim3(256),  0, stream, m_ws, cand);
  hipLaunchKernelGGL(k_topk_p2,     dim3(32),        dim3(256),  0, stream, cand, mtop);
  hipLaunchKernelGGL(k_meanv_part,  dim3(32, 64),    dim3(256),  0, stream, v, vpart);
  hipLaunchKernelGGL(k_meanv_final, dim3(32),        dim3(64),   0, stream, vpart, meanv);
  hipLaunchKernelGGL(k_fill,        dim3(2048),      dim3(256),  0, stream, meanv, (float4*)out);
  hipLaunchKernelGGL(k_scores,      dim3(512),       dim3(1024), 0, stream, q, k, v, mtop, mc, lc, op);
  hipLaunchKernelGGL(k_combine,     dim3(360),       dim3(256),  0, stream, mc, lc, op, mtop, out);
}

// Round 9
// 186.276 us; speedup vs baseline: 1.2390x; 1.0018x over previous
//
#include <hip/hip_runtime.h>
#include <hip/hip_bf16.h>

// ProbAttention (Informer ProbSparse) on MI355X.
// Shapes: queries/keys/values (4, 4096, 8, 64) f32 in (b, l, h, d) layout.
// index_sample (4096, 45) int32. Output context (b, h, 4096, 64) f32.
//
// Pipeline (all fp32 — no fp32 MFMA on CDNA4; precision needed for top-k):
//   K1 compute_m   : m[b,h,l] = max_s(q.k_samp) - sum_s(q.k_samp)/4096
//                    1KB half-block gather, (b,hg)->XCD (L2-resident), DPP
//                    16-lane reduce. Batch-9 register pipeline (9 K-loads in
//                    flight), max3-tree fold, SALU row addressing.
//   K2a topk_p1    : per (b,h,512-slice) top-45 candidates (packed u64 keys)
//   K2b topk_p2    : merge 8x45 candidates -> global top-45 (tie: lowest idx)
//   K3a meanv_part : partial sums of v over l (2048 blocks, full chip)
//   K3b meanv_final: reduce 64 partials -> meanv
//   K3c fill       : out[...] = meanv broadcast (32 MB write)
//   K4 scores      : block=(b,h,chunk of 256), 1024 threads (16 waves ->
//                    32 waves/CU at 2 blocks/CU). QK^T quad-per-key with
//                    coalesced K loads + DPP quad reduce; chunk softmax;
//                    P@V with coalesced V. Partials -> ws.
//   K5 combine     : merge 16 chunk partials, scatter to out rows m_top[u]

#define NB 4
#define NH 8
#define NL 4096
#define ND 64
#define NS 45          // U = n_top = 45
#define SCALE 0.125f   // 1/sqrt(64)
#define NCHUNK 16
#define CHUNK 256

typedef float floatx4 __attribute__((ext_vector_type(4)));

static __device__ __forceinline__ float neg_inf() { return -__builtin_inff(); }

// VALU-pipe cross-lane add via DPP (no DS traffic).
template <int CTRL>
static __device__ __forceinline__ float dpp_add(float x) {
  int y = __builtin_amdgcn_update_dpp(0, __builtin_bit_cast(int, x), CTRL,
                                      0xF, 0xF, true);
  return x + __builtin_bit_cast(float, y);
}
// Sum over 16 contiguous lanes; every lane ends with the group total.
static __device__ __forceinline__ float red16(float x) {
  x = dpp_add<0x140>(x);  // row_mirror      (fold 16 -> 8)
  x = dpp_add<0x141>(x);  // row_half_mirror (fold 8 -> 4)
  x = dpp_add<0x4E>(x);   // quad_perm [2,3,0,1] = xor2
  x = dpp_add<0xB1>(x);   // quad_perm [1,0,3,2] = xor1
  return x;
}
// Sum over each 4-lane quad (butterfly), all 4 lanes get the quad total.
static __device__ __forceinline__ float red4(float x) {
  x = dpp_add<0xB1>(x);   // xor1
  x = dpp_add<0x4E>(x);   // xor2
  return x;
}

// ---------------- K1: sampled-dot m ----------------
// Block per (b, hg, l-group of 4). Wave w = one l. 16-lane group g = head hg*4+g.
// Per sample: 1KB contiguous K half-block (64 lanes x float4), fully coalesced,
// L2-resident (4MB working set per (b,hg) pinned to one XCD via blockIdx&7).
// Samples processed in 5 batches of 9: all 9 loads issued before compute.
__global__ __launch_bounds__(256) void k_compute_m(
    const float* __restrict__ q, const float* __restrict__ k,
    const int* __restrict__ idxs, float* __restrict__ m_out)
{
  __shared__ int sidx[4][48];
  int gb = blockIdx.x;                 // 8192 blocks
  int pair = gb & 7;                   // (b,hg) -> XCD (round-robin dispatch)
  int b = pair >> 1, hg = pair & 1;
  int lg = gb >> 3;                    // 0..1023
  int t = threadIdx.x, w = t >> 6, lane = t & 63, g = lane >> 4;
  int l = lg * 4 + w;

  if (lane < NS) sidx[w][lane] = idxs[l * NS + lane];  // wave-private row

  // Q: heads hg*4..hg*4+3 of row l, 1KB contiguous. Non-temporal (stream once,
  // don't evict the L2-resident K set).
  const floatx4* q4 =
      (const floatx4*)(q + ((size_t)(b * NL + l) * NH + hg * 4) * ND);
  floatx4 qr = __builtin_nontemporal_load(q4 + lane);

  // K half-block base for this (b,hg): row ki at +512 floats each (1KB).
  const float* kbase = k + ((size_t)b * NL * NH + hg * 4) * ND;

  float mx = neg_inf(), sm = 0.f;
#pragma unroll 1
  for (int s0 = 0; s0 < NS; s0 += 9) {
    floatx4 kr[9];
#pragma unroll
    for (int j = 0; j < 9; j++) {
      int ki = __builtin_amdgcn_readfirstlane(sidx[w][s0 + j]);  // SALU addr
      kr[j] = *((const floatx4*)(kbase + (size_t)ki * 512) + lane);
    }
    float p[9];
#pragma unroll
    for (int j = 0; j < 9; j++) {
      float d = kr[j].x * qr.x + kr[j].y * qr.y + kr[j].z * qr.z + kr[j].w * qr.w;
      p[j] = red16(d);                 // 16-lane dot, VALU-only
    }
    // max3-tree fold + reassociated sum (clang fuses fmaxf pairs to v_max3)
    float m0 = fmaxf(fmaxf(p[0], p[1]), p[2]);
    float m1 = fmaxf(fmaxf(p[3], p[4]), p[5]);
    float m2 = fmaxf(fmaxf(p[6], p[7]), p[8]);
    mx = fmaxf(fmaxf(mx, m0), fmaxf(m1, m2));
    sm += ((p[0] + p[1]) + (p[2] + p[3])) +
          ((p[4] + p[5]) + (p[6] + p[7])) + p[8];
  }
  if ((lane & 15) == 0)
    m_out[((size_t)b * NH + hg * 4 + g) * NL + l] = mx - sm * (1.0f / 4096.0f);
}

// ---------------- K2a: per-slice top-45 candidates ----------------
// Block = (bh, 512-slice). Keys: monotone(float) || ~index (exact tie-break).
__global__ __launch_bounds__(256) void k_topk_p1(
    const float* __restrict__ m_in, unsigned long long* __restrict__ cand)
{
  __shared__ unsigned long long keys[512];
  __shared__ unsigned long long wred[4];
  int blk = blockIdx.x;                // bh*8 + slice
  int bh = blk >> 3, slice = blk & 7;
  int t = threadIdx.x, wid = t >> 6, lane = t & 63;
  int base = slice * 512;
  for (int i = t; i < 512; i += 256) {
    float v = m_in[bh * NL + base + i];
    unsigned u = __float_as_uint(v);
    u ^= (u >> 31) ? 0xFFFFFFFFu : 0x80000000u;  // monotone mapping
    keys[i] = ((unsigned long long)u << 32) | (unsigned)(~(unsigned)(base + i));
  }
  __syncthreads();
  for (int it = 0; it < NS; ++it) {
    unsigned long long k0 = keys[t], k1 = keys[t + 256];
    unsigned long long best = k0 > k1 ? k0 : k1;
#pragma unroll
    for (int off = 32; off; off >>= 1) {
      unsigned long long o = __shfl_xor(best, off);
      if (o > best) best = o;
    }
    if (lane == 0) wred[wid] = best;
    __syncthreads();
    if (t == 0) {
      unsigned long long b0 = wred[0];
      if (wred[1] > b0) b0 = wred[1];
      if (wred[2] > b0) b0 = wred[2];
      if (wred[3] > b0) b0 = wred[3];
      cand[blk * NS + it] = b0;
      int gi = (int)(~(unsigned)(b0 & 0xFFFFFFFFull));
      keys[gi - base] = 0;
    }
    __syncthreads();
  }
}

// ---------------- K2b: merge 8x45 candidates -> top-45 ----------------
__global__ __launch_bounds__(256) void k_topk_p2(
    const unsigned long long* __restrict__ cand, int* __restrict__ mtop)
{
  __shared__ unsigned long long keys[8 * NS];  // 360
  __shared__ unsigned long long wred[4];
  __shared__ unsigned long long sbest;
  int bh = blockIdx.x;
  int t = threadIdx.x, wid = t >> 6, lane = t & 63;
  for (int i = t; i < 8 * NS; i += 256) keys[i] = cand[bh * 8 * NS + i];
  __syncthreads();
  for (int it = 0; it < NS; ++it) {
    unsigned long long best = (t < 8 * NS) ? keys[t] : 0ull;
    if (t + 256 < 8 * NS) {
      unsigned long long k1 = keys[t + 256];
      if (k1 > best) best = k1;
    }
#pragma unroll
    for (int off = 32; off; off >>= 1) {
      unsigned long long o = __shfl_xor(best, off);
      if (o > best) best = o;
    }
    if (lane == 0) wred[wid] = best;
    __syncthreads();
    if (t == 0) {
      unsigned long long b0 = wred[0];
      if (wred[1] > b0) b0 = wred[1];
      if (wred[2] > b0) b0 = wred[2];
      if (wred[3] > b0) b0 = wred[3];
      sbest = b0;
      mtop[bh * NS + it] = (int)(~(unsigned)(b0 & 0xFFFFFFFFull));
    }
    __syncthreads();
    unsigned long long bb = sbest;     // keys are unique -> exact match zeroing
    if (t < 8 * NS && keys[t] == bb) keys[t] = 0;
    if (t + 256 < 8 * NS && keys[t + 256] == bb) keys[t + 256] = 0;
    __syncthreads();
  }
}

// ---------------- K3a: partial mean of v over l ----------------
// grid (32 bh, 64 chunks); block sums 64 consecutive l rows.
__global__ __launch_bounds__(256) void k_meanv_part(
    const float* __restrict__ v, float* __restrict__ vpart)
{
  __shared__ float part[4][ND];
  int bh = blockIdx.x, c = blockIdx.y;
  int b = bh >> 3, h = bh & 7;
  int t = threadIdx.x, d = t & 63, g = t >> 6;
  float a0 = 0.f, a1 = 0.f, a2 = 0.f, a3 = 0.f;
  const float* vb = v + ((size_t)(b * NL + c * 64) * NH + h) * ND + d;
#pragma unroll
  for (int i = 0; i < 4; i++) {
    a0 += vb[(size_t)(g + 4 * (4 * i + 0)) * NH * ND];
    a1 += vb[(size_t)(g + 4 * (4 * i + 1)) * NH * ND];
    a2 += vb[(size_t)(g + 4 * (4 * i + 2)) * NH * ND];
    a3 += vb[(size_t)(g + 4 * (4 * i + 3)) * NH * ND];
  }
  part[g][d] = (a0 + a1) + (a2 + a3);
  __syncthreads();
  if (g == 0) {
    float s = part[0][d] + part[1][d] + part[2][d] + part[3][d];
    vpart[(bh * 64 + c) * ND + d] = s;
  }
}

// ---------------- K3b: reduce partials -> meanv ----------------
__global__ __launch_bounds__(64) void k_meanv_final(
    const float* __restrict__ vpart, float* __restrict__ meanv)
{
  int bh = blockIdx.x, d = threadIdx.x;
  float s = 0.f;
  for (int c = 0; c < 64; c++) s += vpart[(bh * 64 + c) * ND + d];
  meanv[bh * ND + d] = s * (1.0f / 4096.0f);
}

// ---------------- K3c: fill output with meanv ----------------
__global__ __launch_bounds__(256) void k_fill(
    const float* __restrict__ meanv, float4* __restrict__ out4)
{
  const int total = NB * NH * NL * ND / 4;  // 2M float4
  const float4* mv4 = (const float4*)meanv;
  for (int i = blockIdx.x * 256 + threadIdx.x; i < total; i += gridDim.x * 256) {
    int bh = i >> 16;       // 65536 float4 per (b,h)
    int d4 = i & 15;
    out4[i] = mv4[bh * 16 + d4];
  }
}

// ---------------- K4: scores+softmax+PV partials (16 waves/block) ----------------
// Block = (b,h, chunk of 256 keys), 1024 threads = 16 waves.
// Phase B: quad-per-key QK^T, coalesced K, DPP quad reduce (one pass, 16 keys/wave).
// Phase B2: full-chunk softmax per row.  Phase C: P@V, coalesced V, 3 rows/wave.
__global__ __launch_bounds__(1024) void k_scores(
    const float* __restrict__ q, const float* __restrict__ k,
    const float* __restrict__ v, const int* __restrict__ mtop,
    float* __restrict__ mc_out, float* __restrict__ lc_out,
    float* __restrict__ op_out)
{
  __shared__ float QLDS[NS * ND];     // 45x64 = 11.5KB
  __shared__ float SLDS[NS * 260];    // 45 rows, 260-stride (pad) = 46.8KB
  __shared__ int mt[NS];
  __shared__ float mcs[NS], lcs[NS];

  int gb = blockIdx.x;
  int xcd = gb & 7, seq = gb >> 3;    // 512 blocks: 4 bh per XCD
  int bh = xcd * 4 + (seq >> 4);
  int c = seq & 15;
  int b = bh >> 3, h = bh & 7;
  int t = threadIdx.x;                // 0..1023
  int wid = t >> 6, lane = t & 63;

  if (t < NS) mt[t] = mtop[bh * NS + t];
  __syncthreads();

  // stage Qr (45 rows) into LDS: 720 float4, one per thread t<720
  const float4* q4 = (const float4*)q;
  float4* QL4 = (float4*)QLDS;
  if (t < NS * 16) {
    int u = t >> 4, j = t & 15;
    QL4[t] = q4[((size_t)(b * NL + mt[u]) * NH + h) * 16 + j];
  }
  __syncthreads();

  // Phase B: quad owns key kk; lane holds contiguous 64B segment of K row.
  {
    int kk = wid * 16 + (lane >> 2);   // 0..255 (16 waves x 16 keys)
    int seg = lane & 3;
    const float4* k4 =
        (const float4*)(k + ((size_t)(b * NL + c * CHUNK + kk) * NH + h) * ND)
        + seg * 4;
    float4 k0 = k4[0], k1 = k4[1], k2 = k4[2], k3 = k4[3];
    const float4* qp = QL4 + seg * 4;
    for (int u = 0; u < NS; ++u) {
      float4 a0 = qp[u * 16 + 0], a1 = qp[u * 16 + 1];
      float4 a2 = qp[u * 16 + 2], a3 = qp[u * 16 + 3];
      float dot = a0.x * k0.x + a0.y * k0.y + a0.z * k0.z + a0.w * k0.w
                + a1.x * k1.x + a1.y * k1.y + a1.z * k1.z + a1.w * k1.w
                + a2.x * k2.x + a2.y * k2.y + a2.z * k2.z + a2.w * k2.w
                + a3.x * k3.x + a3.y * k3.y + a3.z * k3.z + a3.w * k3.w;
      dot = red4(dot);                 // quad total, VALU-only
      if (seg == 0) SLDS[u * 260 + kk] = dot * SCALE;
    }
  }
  __syncthreads();

  // Phase B2: per-row chunk softmax (max, exp, sum), exp written back.
  for (int u = wid; u < NS; u += 16) {
    float4 sv = *(const float4*)&SLDS[u * 260 + lane * 4];
    float mx = fmaxf(fmaxf(sv.x, sv.y), fmaxf(sv.z, sv.w));
#pragma unroll
    for (int off = 32; off; off >>= 1) mx = fmaxf(mx, __shfl_xor(mx, off));
    float e0 = expf(sv.x - mx), e1 = expf(sv.y - mx);
    float e2 = expf(sv.z - mx), e3 = expf(sv.w - mx);
    float s = e0 + e1 + e2 + e3;
#pragma unroll
    for (int off = 32; off; off >>= 1) s += __shfl_xor(s, off);
    *(float4*)&SLDS[u * 260 + lane * 4] = make_float4(e0, e1, e2, e3);
    if (lane == 0) { mcs[u] = mx; lcs[u] = s; }
  }
  __syncthreads();

  // Phase C: O_partial = P @ V_chunk. Wave w owns rows u = w+16i; lane = d.
  float acc[3];
#pragma unroll
  for (int i = 0; i < 3; i++) acc[i] = 0.f;
  const float* vbase = v + ((size_t)(b * NL + c * CHUNK) * NH + h) * ND + lane;
  for (int kb = 0; kb < 64; ++kb) {
    float vd0 = vbase[(size_t)(kb * 4 + 0) * NH * ND];
    float vd1 = vbase[(size_t)(kb * 4 + 1) * NH * ND];
    float vd2 = vbase[(size_t)(kb * 4 + 2) * NH * ND];
    float vd3 = vbase[(size_t)(kb * 4 + 3) * NH * ND];
#pragma unroll
    for (int i = 0; i < 3; i++) {
      int u = wid + 16 * i;
      if (u < NS) {
        float4 p4 = *(const float4*)&SLDS[u * 260 + kb * 4];  // broadcast
        acc[i] += p4.x * vd0 + p4.y * vd1 + p4.z * vd2 + p4.w * vd3;
      }
    }
  }
#pragma unroll
  for (int i = 0; i < 3; i++) {
    int u = wid + 16 * i;
    if (u < NS)
      op_out[(((size_t)bh * NCHUNK + c) * NS + u) * ND + lane] = acc[i];
  }
  if (t < NS) {
    mc_out[(bh * NCHUNK + c) * NS + t] = mcs[t];
    lc_out[(bh * NCHUNK + c) * NS + t] = lcs[t];
  }
}

// ---------------- K5: combine partials + scatter ----------------
__global__ __launch_bounds__(256) void k_combine(
    const float* __restrict__ mc, const float* __restrict__ lc,
    const float* __restrict__ op, const int* __restrict__ mtop,
    float* __restrict__ out)
{
  int gw = blockIdx.x * 4 + (threadIdx.x >> 6);  // 1440 waves
  int lane = threadIdx.x & 63;
  int bh = gw / NS, u = gw % NS;
  float M = neg_inf();
  for (int c = 0; c < NCHUNK; c++)
    M = fmaxf(M, mc[(bh * NCHUNK + c) * NS + u]);
  float Lsum = 0.f, O = 0.f;
  for (int c = 0; c < NCHUNK; c++) {
    float e = expf(mc[(bh * NCHUNK + c) * NS + u] - M);
    Lsum += lc[(bh * NCHUNK + c) * NS + u] * e;
    O += op[(((size_t)bh * NCHUNK + c) * NS + u) * ND + lane] * e;
  }
  int row = mtop[bh * NS + u];
  out[((size_t)bh * NL + row) * ND + lane] = O / Lsum;
}

extern "C" void kernel_launch(void* const* d_in, const int* in_sizes, int n_in,
                              void* d_out, int out_size, void* d_ws, size_t ws_size,
                              hipStream_t stream) {
  const float* q = (const float*)d_in[0];
  const float* k = (const float*)d_in[1];
  const float* v = (const float*)d_in[2];
  const int* idxs = (const int*)d_in[3];
  float* out = (float*)d_out;
  float* ws = (float*)d_ws;

  // workspace layout (floats): total ~1.66M floats = 6.62 MB
  float* m_ws  = ws;                    // 131072
  int*   mtop  = (int*)(ws + 131072);   // 1440 ints
  float* meanv = ws + 132512;           // 2048
  float* mc    = ws + 134560;           // 32*16*45 = 23040
  float* lc    = ws + 157600;           // 23040
  float* op    = ws + 180640;           // 32*16*45*64 = 1474560
  // Aliases inside op (consumed before k_scores writes op; serial stream):
  //   vpart: op[0 .. 131072)           (meanv partials)
  //   cand : op[131072 .. 154112)      (topk candidates, 11520 u64)
  float* vpart = op;
  unsigned long long* cand = (unsigned long long*)(op + 131072);

  hipLaunchKernelGGL(k_compute_m,   dim3(8192),      dim3(256),  0, stream, q, k, idxs, m_ws);
  hipLaunchKernelGGL(k_topk_p1,     dim3(256),       dim3(256),  0, stream, m_ws, cand);
  hipLaunchKernelGGL(k_topk_p2,     dim3(32),        dim3(256),  0, stream, cand, mtop);
  hipLaunchKernelGGL(k_meanv_part,  dim3(32, 64),    dim3(256),  0, stream, v, vpart);
  hipLaunchKernelGGL(k_meanv_final, dim3(32),        dim3(64),   0, stream, vpart, meanv);
  hipLaunchKernelGGL(k_fill,        dim3(2048),      dim3(256),  0, stream, meanv, (float4*)out);
  hipLaunchKernelGGL(k_scores,      dim3(512),       dim3(1024), 0, stream, q, k, v, mtop, mc, lc, op);
  hipLaunchKernelGGL(k_combine,     dim3(360),       dim3(256),  0, stream, mc, lc, op, mtop, out);
}